// Round 3
// baseline (15296.185 us; speedup 1.0000x reference)
//
#include <hip/hip_runtime.h>
#include <stdint.h>

// ===========================================================================
// CORRECTNESS-BISECT ROUND: pure fp32, no MFMA, no bf16, no LDS tricks.
// Tests ONLY the algebraic reduction of the reference:
//   * stack slots are provably identical (mem0 = 0, broadcast update), so the
//     memory attention is exactly uniform -> Mq_*, Mk_* unused,
//     read = ptr_mass * (m @ Mv_full),  ptr_mass *= gsum / (gsum + EPS).
//   * complex linear = [zr|zi] @ [[Wr, Wi], [-Wi, Wr]]  (W stored [in][out]).
// ===========================================================================

constexpr float QK_SCALE = 0.08838834764831845f;  // 128^-0.5  (ref: D**-0.5)

__global__ void n_init(const float* __restrict__ xr, const float* __restrict__ xi,
                       float* __restrict__ Z, float* __restrict__ Mm,
                       float* __restrict__ PSUM){
  for (int i = blockIdx.x*blockDim.x + threadIdx.x; i < 8192*256; i += gridDim.x*blockDim.x){
    int n = i >> 8, d = i & 255;
    Z[i]  = (d < 128) ? xr[n*128 + d] : xi[n*128 + d - 128];
    Mm[i] = 0.f;
    if (i < 8192) PSUM[i] = 1.f;
  }
}

// QKV projection: one block per (row n, section sec). sec 0/1/2 = q/k/v.
// out[n][sec*256 + t],  t = half*128 + cc:
//   half 0:  sum_d  zr[d]*Wr[d][cc] - zi[d]*Wi[d][cc]
//   half 1:  sum_d  zi[d]*Wr[d][cc] + zr[d]*Wi[d][cc]
__global__ void n_proj(const float* __restrict__ Z,
                       const float* __restrict__ Wq_r, const float* __restrict__ Wq_i,
                       const float* __restrict__ Wk_r, const float* __restrict__ Wk_i,
                       const float* __restrict__ Wv_r, const float* __restrict__ Wv_i,
                       float* __restrict__ QKV){
  __shared__ float zrow[256];
  const int n = blockIdx.x, sec = blockIdx.y, t = threadIdx.x;
  zrow[t] = Z[n*256 + t];
  __syncthreads();
  const float* Wr = (sec == 0) ? Wq_r : (sec == 1) ? Wk_r : Wv_r;
  const float* Wi = (sec == 0) ? Wq_i : (sec == 1) ? Wk_i : Wv_i;
  const int cc = t & 127, half = t >> 7;
  float s = 0.f;
  if (half == 0){
    for (int d = 0; d < 128; ++d)
      s += zrow[d]*Wr[d*128 + cc] - zrow[128 + d]*Wi[d*128 + cc];
  } else {
    for (int d = 0; d < 128; ++d)
      s += zrow[128 + d]*Wr[d*128 + cc] + zrow[d]*Wi[d*128 + cc];
  }
  QKV[(size_t)n*768 + sec*256 + t] = s;
}

// Sequence attention: one block (256 thr) per q row. Scores over the full
// 2D=256-dim concat feature, softmax over 1024 keys, PV -> ZF[n][256].
__global__ void n_attn(const float* __restrict__ QKV, float* __restrict__ ZF){
  __shared__ float q[256];
  __shared__ float sc[1024];
  __shared__ float red[256];
  const int n = blockIdx.x, t = threadIdx.x;
  const int batch = n >> 10;
  q[t] = QKV[(size_t)n*768 + t];
  __syncthreads();
  #pragma unroll 1
  for (int k4 = 0; k4 < 4; ++k4){
    const int key = k4*256 + t;
    const float* kf = QKV + (size_t)(batch*1024 + key)*768 + 256;
    float s = 0.f;
    for (int d = 0; d < 256; ++d) s += q[d]*kf[d];
    sc[key] = s * QK_SCALE;
  }
  float mx = -1.0e30f;
  #pragma unroll
  for (int k4 = 0; k4 < 4; ++k4) mx = fmaxf(mx, sc[k4*256 + t]);
  __syncthreads();
  red[t] = mx;
  __syncthreads();
  for (int s2 = 128; s2 > 0; s2 >>= 1){
    if (t < s2) red[t] = fmaxf(red[t], red[t + s2]);
    __syncthreads();
  }
  const float m = red[0];
  __syncthreads();
  float sum = 0.f;
  #pragma unroll
  for (int k4 = 0; k4 < 4; ++k4){
    float p = expf(sc[k4*256 + t] - m);
    sc[k4*256 + t] = p;
    sum += p;
  }
  red[t] = sum;
  __syncthreads();
  for (int s2 = 128; s2 > 0; s2 >>= 1){
    if (t < s2) red[t] += red[t + s2];
    __syncthreads();
  }
  const float inv = 1.f / red[0];
  // PV: thread t = output dim d. Per iteration all 256 threads read
  // consecutive addresses of one V row (coalesced), sc[key] broadcasts.
  float o = 0.f;
  const float* vbase = QKV + (size_t)(batch*1024)*768 + 512 + t;
  #pragma unroll 1
  for (int key = 0; key < 1024; ++key) o += sc[key] * vbase[(size_t)key*768];
  ZF[n*256 + t] = o * inv;
}

// Gate + memory + pointer-mass update: one block per row.
__global__ void n_gate(const float* __restrict__ ZF,
                       const float* __restrict__ Wc, const float* __restrict__ bc,
                       float* __restrict__ Mm, float* __restrict__ PSUM){
  __shared__ float r0[256], r1[256], r2[256];
  __shared__ float push_s;
  const int n = blockIdx.x, t = threadIdx.x;
  const float z = ZF[n*256 + t];
  r0[t] = z*Wc[t*3 + 0];
  r1[t] = z*Wc[t*3 + 1];
  r2[t] = z*Wc[t*3 + 2];
  __syncthreads();
  for (int s2 = 128; s2 > 0; s2 >>= 1){
    if (t < s2){ r0[t] += r0[t+s2]; r1[t] += r1[t+s2]; r2[t] += r2[t+s2]; }
    __syncthreads();
  }
  if (t == 0){
    float g0 = 1.f/(1.f + expf(-(r0[0] + bc[0])));
    float g1 = 1.f/(1.f + expf(-(r1[0] + bc[1])));
    float g2 = 1.f/(1.f + expf(-(r2[0] + bc[2])));
    float tt = g0 + g1 + g2, tot = tt + 1e-6f;
    push_s = g0/tot;
    PSUM[n] *= tt/tot;           // pointer mass with the NEW gates
  }
  __syncthreads();
  const float mo = Mm[n*256 + t];
  Mm[n*256 + t] = mo + push_s*(z - mo);   // (1-push)*m + push*zf
}

// Memory read (uniform attention collapses to m @ Mv_full) + residual:
// Z[n][t] = ZF[n][t] + 0.1 * PSUM[n] * (clinear(m_r, m_i, Mv_r, Mv_i))[t]
__global__ void n_memread(const float* __restrict__ Mm,
                          const float* __restrict__ Mv_r, const float* __restrict__ Mv_i,
                          const float* __restrict__ ZF, const float* __restrict__ PSUM,
                          float* __restrict__ Z){
  __shared__ float mrow[256];
  const int n = blockIdx.x, t = threadIdx.x;
  mrow[t] = Mm[n*256 + t];
  __syncthreads();
  const int cc = t & 127, half = t >> 7;
  float s = 0.f;
  if (half == 0){
    for (int d = 0; d < 128; ++d)
      s += mrow[d]*Mv_r[d*128 + cc] - mrow[128 + d]*Mv_i[d*128 + cc];
  } else {
    for (int d = 0; d < 128; ++d)
      s += mrow[128 + d]*Mv_r[d*128 + cc] + mrow[d]*Mv_i[d*128 + cc];
  }
  // ZF may alias Z: each thread reads its own element before writing it.
  const float zf = ZF[n*256 + t];
  Z[n*256 + t] = zf + 0.1f * PSUM[n] * s;
}

// Final modulus projection: out[n][t] = Z[n][:] @ Wo[:,t] + bo[t]
__global__ void n_out(const float* __restrict__ Z,
                      const float* __restrict__ Wo, const float* __restrict__ bo,
                      float* __restrict__ out){
  __shared__ float zrow[256];
  const int n = blockIdx.x, t = threadIdx.x;
  zrow[t] = Z[n*256 + t];
  __syncthreads();
  if (t < 128){
    float s = 0.f;
    for (int k = 0; k < 256; ++k) s += zrow[k]*Wo[k*128 + t];
    out[n*128 + t] = s + bo[t];
  }
}

// ---------------------------------------------------------------------------
extern "C" void kernel_launch(void* const* d_in, const int* in_sizes, int n_in,
                              void* d_out, int out_size, void* d_ws, size_t ws_size,
                              hipStream_t stream){
  (void)in_sizes; (void)n_in; (void)out_size; (void)ws_size;
  const float* xr   = (const float*)d_in[0];
  const float* xi   = (const float*)d_in[1];
  const float* Wq_r = (const float*)d_in[2];
  const float* Wq_i = (const float*)d_in[3];
  const float* Wk_r = (const float*)d_in[4];
  const float* Wk_i = (const float*)d_in[5];
  const float* Wv_r = (const float*)d_in[6];
  const float* Wv_i = (const float*)d_in[7];
  // d_in[8..11] (Mq_*, Mk_*) unused: all stack slots identical -> memory
  // attention is exactly uniform regardless of its q/k projections.
  const float* Mv_r = (const float*)d_in[12];
  const float* Mv_i = (const float*)d_in[13];
  const float* Wc   = (const float*)d_in[14];
  const float* bc   = (const float*)d_in[15];
  const float* Wo   = (const float*)d_in[16];
  const float* bo   = (const float*)d_in[17];

  uint8_t* w = (uint8_t*)d_ws;
  float* Z    = (float*)w; w += (size_t)8192*256*4;   // state (aliased as ZF)
  float* QKV  = (float*)w; w += (size_t)8192*768*4;   // projections
  float* Mm   = (float*)w; w += (size_t)8192*256*4;   // stack-memory value
  float* PSUM = (float*)w; w += (size_t)8192*4;       // pointer mass
  float* ZF   = Z;  // safe alias: state is dead once n_proj has consumed it;
                    // n_memread's rewrite is elementwise read-before-write.

  n_init<<<dim3(1024), dim3(256), 0, stream>>>(xr, xi, Z, Mm, PSUM);
  for (int t = 0; t < 8; ++t){
    n_proj<<<dim3(8192, 3), dim3(256), 0, stream>>>(Z, Wq_r, Wq_i, Wk_r, Wk_i,
                                                    Wv_r, Wv_i, QKV);
    n_attn<<<dim3(8192), dim3(256), 0, stream>>>(QKV, ZF);
    n_gate<<<dim3(8192), dim3(256), 0, stream>>>(ZF, Wc, bc, Mm, PSUM);
    n_memread<<<dim3(8192), dim3(256), 0, stream>>>(Mm, Mv_r, Mv_i, ZF, PSUM, Z);
  }
  n_out<<<dim3(8192), dim3(256), 0, stream>>>(Z, Wo, bo, (float*)d_out);
}

// Round 6
// 3321.445 us; speedup vs baseline: 4.6053x; 4.6053x over previous
//
#include <hip/hip_runtime.h>
#include <stdint.h>

typedef __attribute__((ext_vector_type(4))) float f32x4;

constexpr float QK_SCALE = 0.08838834764831845f;  // 128^-0.5

// ===========================================================================
// All-fp32 pipeline. bf16/MFMA is numerically forbidden here: the 8-step
// recursion amplifies per-step noise by ~1e3-1e4 (verified r3 vs r4/r5), so
// bf16's 4e-3 rel noise saturates the output (absmax ~31 vs threshold 0.47).
// Dataflow graph is identical to the verified round-3 implementation.
// ===========================================================================

__global__ void k_init32(const float* __restrict__ xr, const float* __restrict__ xi,
                         float* __restrict__ Z, float* __restrict__ Mm,
                         float* __restrict__ PSUM){
  for (int i = blockIdx.x*blockDim.x + threadIdx.x; i < 8192*256; i += gridDim.x*blockDim.x){
    int n = i >> 8, d = i & 255;
    Z[i]  = (d < 128) ? xr[n*128 + d] : xi[n*128 + d - 128];
    Mm[i] = 0.f;
    if (i < 8192) PSUM[i] = 1.f;
  }
}

// ---------------- tiled fp32 GEMM: C[M x N] = A[M x 256] @ Wfull[256 x N] ---
// Wfull is materialized on the fly from (Wr, Wi) 128x128 blocks:
//   [[Wr, Wi], [-Wi, Wr]]  (EPI 0/1);  EPI 2 reads Wo [256][128] directly.
// EPI 0: C = QKV (ldc 768, sec from n0)   EPI 1: Z += 0.1*PSUM[row]*acc (ldc 256)
// EPI 2: out = acc + bias (ldc 128)
template<int EPI>
__launch_bounds__(256, 2)
__global__ void k_gemm32(const float* __restrict__ A, int nb,
                         const float* __restrict__ W0r, const float* __restrict__ W0i,
                         const float* __restrict__ W1r, const float* __restrict__ W1i,
                         const float* __restrict__ W2r, const float* __restrict__ W2i,
                         float* __restrict__ C, const float* __restrict__ PSUM,
                         const float* __restrict__ bias){
  __shared__ float As[32][132];   // [k][m], padded
  __shared__ float Bs[32][132];   // [k][n], padded
  const int bx = blockIdx.x % nb, by = blockIdx.x / nb;
  const int m0 = by << 7, n0 = bx << 7;
  const int tid = threadIdx.x;
  const int tx = tid & 15, ty = tid >> 4;
  const float* Wr = W0r; const float* Wi = W0i;
  if constexpr (EPI == 0){
    int sec = n0 >> 8;
    Wr = (sec == 0) ? W0r : (sec == 1) ? W1r : W2r;
    Wi = (sec == 0) ? W0i : (sec == 1) ? W1i : W2i;
  }
  const int hn = (n0 >> 7) & 1;
  float acc[8][8];
  #pragma unroll
  for (int i = 0; i < 8; ++i)
    #pragma unroll
    for (int j = 0; j < 8; ++j) acc[i][j] = 0.f;

  for (int kt = 0; kt < 8; ++kt){
    if (kt) __syncthreads();
    #pragma unroll
    for (int i = 0; i < 4; ++i){               // A tile: transpose-scatter
      int c = i*256 + tid;                     // [0,1024) f4 units
      int row = c >> 3, k4 = c & 7;
      f32x4 v = *(const f32x4*)&A[(size_t)(m0 + row)*256 + kt*32 + k4*4];
      As[k4*4+0][row] = v.x; As[k4*4+1][row] = v.y;
      As[k4*4+2][row] = v.z; As[k4*4+3][row] = v.w;
    }
    #pragma unroll
    for (int i = 0; i < 4; ++i){               // B tile: on-the-fly Wfull
      int c = i*256 + tid;
      int k = c >> 5, n4 = c & 31;
      int gk = kt*32 + k;
      f32x4 v;
      if constexpr (EPI == 2){
        v = *(const f32x4*)&W0r[(size_t)gk*128 + n4*4];
      } else {
        int hk = gk >> 7, kk = gk & 127;
        const float* src = ((hk ^ hn) == 0) ? Wr : Wi;
        v = *(const f32x4*)&src[(size_t)kk*128 + n4*4];
        if (hk == 1 && hn == 0){ v.x = -v.x; v.y = -v.y; v.z = -v.z; v.w = -v.w; }
      }
      *(f32x4*)&Bs[k][n4*4] = v;
    }
    __syncthreads();
    #pragma unroll 8
    for (int k = 0; k < 32; ++k){
      float a[8], b[8];
      *(f32x4*)&a[0] = *(const f32x4*)&As[k][ty*8];
      *(f32x4*)&a[4] = *(const f32x4*)&As[k][ty*8 + 4];
      *(f32x4*)&b[0] = *(const f32x4*)&Bs[k][tx*8];
      *(f32x4*)&b[4] = *(const f32x4*)&Bs[k][tx*8 + 4];
      #pragma unroll
      for (int i = 0; i < 8; ++i)
        #pragma unroll
        for (int j = 0; j < 8; ++j) acc[i][j] += a[i]*b[j];
    }
  }
  #pragma unroll
  for (int i = 0; i < 8; ++i){
    const int row = m0 + ty*8 + i;
    const int col = n0 + tx*8;
    if constexpr (EPI == 0){
      *(f32x4*)&C[(size_t)row*768 + col]     = *(const f32x4*)&acc[i][0];
      *(f32x4*)&C[(size_t)row*768 + col + 4] = *(const f32x4*)&acc[i][4];
    } else if constexpr (EPI == 1){
      const float s = 0.1f * PSUM[row];
      f32x4 z0 = *(const f32x4*)&C[(size_t)row*256 + col];
      f32x4 z1 = *(const f32x4*)&C[(size_t)row*256 + col + 4];
      z0.x += s*acc[i][0]; z0.y += s*acc[i][1]; z0.z += s*acc[i][2]; z0.w += s*acc[i][3];
      z1.x += s*acc[i][4]; z1.y += s*acc[i][5]; z1.z += s*acc[i][6]; z1.w += s*acc[i][7];
      *(f32x4*)&C[(size_t)row*256 + col]     = z0;
      *(f32x4*)&C[(size_t)row*256 + col + 4] = z1;
    } else {
      f32x4 b0 = *(const f32x4*)&bias[col];
      f32x4 b1 = *(const f32x4*)&bias[col + 4];
      f32x4 o0 = {acc[i][0]+b0.x, acc[i][1]+b0.y, acc[i][2]+b0.z, acc[i][3]+b0.w};
      f32x4 o1 = {acc[i][4]+b1.x, acc[i][5]+b1.y, acc[i][6]+b1.z, acc[i][7]+b1.w};
      *(f32x4*)&C[(size_t)row*128 + col]     = o0;
      *(f32x4*)&C[(size_t)row*128 + col + 4] = o1;
    }
  }
}

// ---------------- fp32 flash attention: 32 q-rows per block -----------------
// grid 256 (8 batches x 32 q-tiles), 256 thr (tx=16 cols, ty=16 -> 2 q-rows).
// Online softmax in registers; K staged transposed [d][k], V direct [k][d]
// into a shared 16KB chunk buffer; P via padded LDS [k][34].
__launch_bounds__(256, 2)
__global__ void k_attn32(const float* __restrict__ QKV, float* __restrict__ ZF){
  __shared__ float Qs[256][32];    // [d][q]  32 KB
  __shared__ float KVs[64][64];    // K: [d][k] / V: [k][d]  16 KB
  __shared__ float Ps[64][34];     // [k][q]  8.5 KB
  const int tid = threadIdx.x;
  const int tx = tid & 15, ty = tid >> 4;
  const int nbase = blockIdx.x << 5;
  const int kv0 = (blockIdx.x >> 5) << 10;

  #pragma unroll
  for (int i = 0; i < 8; ++i){               // stage Q transposed
    int c = i*256 + tid;                     // [0,2048) f4 units
    int q = c >> 6, d4 = c & 63;
    f32x4 v = *(const f32x4*)&QKV[(size_t)(nbase + q)*768 + d4*4];
    Qs[d4*4+0][q] = v.x; Qs[d4*4+1][q] = v.y;
    Qs[d4*4+2][q] = v.z; Qs[d4*4+3][q] = v.w;
  }
  float O[2][16];
  #pragma unroll
  for (int j = 0; j < 2; ++j)
    #pragma unroll
    for (int e = 0; e < 16; ++e) O[j][e] = 0.f;
  float mrow[2] = {-3.0e30f, -3.0e30f}, lrow[2] = {0.f, 0.f};

  for (int t = 0; t < 16; ++t){
    float S[2][4] = {{0.f,0.f,0.f,0.f},{0.f,0.f,0.f,0.f}};
    for (int dc = 0; dc < 4; ++dc){
      __syncthreads();                       // prev KVs reads done
      #pragma unroll
      for (int i = 0; i < 4; ++i){           // stage K chunk transposed
        int c = i*256 + tid;                 // [0,1024)
        int k = c >> 4, d4 = c & 15;
        f32x4 v = *(const f32x4*)&QKV[(size_t)(kv0 + t*64 + k)*768 + 256 + dc*64 + d4*4];
        KVs[d4*4+0][k] = v.x; KVs[d4*4+1][k] = v.y;
        KVs[d4*4+2][k] = v.z; KVs[d4*4+3][k] = v.w;
      }
      __syncthreads();
      #pragma unroll 16
      for (int d = 0; d < 64; ++d){
        float q0 = Qs[dc*64 + d][ty*2];
        float q1 = Qs[dc*64 + d][ty*2 + 1];
        f32x4 kk = *(const f32x4*)&KVs[d][tx*4];
        S[0][0] += q0*kk.x; S[0][1] += q0*kk.y; S[0][2] += q0*kk.z; S[0][3] += q0*kk.w;
        S[1][0] += q1*kk.x; S[1][1] += q1*kk.y; S[1][2] += q1*kk.z; S[1][3] += q1*kk.w;
      }
    }
    #pragma unroll
    for (int j = 0; j < 2; ++j){
      #pragma unroll
      for (int e = 0; e < 4; ++e) S[j][e] *= QK_SCALE;
      float tm = fmaxf(fmaxf(S[j][0], S[j][1]), fmaxf(S[j][2], S[j][3]));
      tm = fmaxf(tm, __shfl_xor(tm, 1));
      tm = fmaxf(tm, __shfl_xor(tm, 2));
      tm = fmaxf(tm, __shfl_xor(tm, 4));
      tm = fmaxf(tm, __shfl_xor(tm, 8));
      const float mnew = fmaxf(mrow[j], tm);
      const float alpha = expf(mrow[j] - mnew);
      float p[4], rs = 0.f;
      #pragma unroll
      for (int e = 0; e < 4; ++e){ p[e] = expf(S[j][e] - mnew); rs += p[e]; }
      rs += __shfl_xor(rs, 1);
      rs += __shfl_xor(rs, 2);
      rs += __shfl_xor(rs, 4);
      rs += __shfl_xor(rs, 8);
      lrow[j] = lrow[j]*alpha + rs;
      mrow[j] = mnew;
      #pragma unroll
      for (int e = 0; e < 16; ++e) O[j][e] *= alpha;
      #pragma unroll
      for (int e = 0; e < 4; ++e) Ps[tx*4 + e][ty*2 + j] = p[e];
    }
    __syncthreads();                         // P visible; QK reads done
    for (int dc = 0; dc < 4; ++dc){
      if (dc) __syncthreads();
      #pragma unroll
      for (int i = 0; i < 4; ++i){           // stage V chunk direct
        int c = i*256 + tid;
        int k = c >> 4, d4 = c & 15;
        f32x4 v = *(const f32x4*)&QKV[(size_t)(kv0 + t*64 + k)*768 + 512 + dc*64 + d4*4];
        *(f32x4*)&KVs[k][d4*4] = v;
      }
      __syncthreads();
      #pragma unroll 16
      for (int k = 0; k < 64; ++k){
        float p0 = Ps[k][ty*2];
        float p1 = Ps[k][ty*2 + 1];
        f32x4 vv = *(const f32x4*)&KVs[k][tx*4];
        O[0][dc*4+0] += p0*vv.x; O[0][dc*4+1] += p0*vv.y;
        O[0][dc*4+2] += p0*vv.z; O[0][dc*4+3] += p0*vv.w;
        O[1][dc*4+0] += p1*vv.x; O[1][dc*4+1] += p1*vv.y;
        O[1][dc*4+2] += p1*vv.z; O[1][dc*4+3] += p1*vv.w;
      }
    }
  }
  const float inv0 = 1.f / lrow[0], inv1 = 1.f / lrow[1];
  #pragma unroll
  for (int dc = 0; dc < 4; ++dc){
    f32x4 w0 = {O[0][dc*4+0]*inv0, O[0][dc*4+1]*inv0, O[0][dc*4+2]*inv0, O[0][dc*4+3]*inv0};
    f32x4 w1 = {O[1][dc*4+0]*inv1, O[1][dc*4+1]*inv1, O[1][dc*4+2]*inv1, O[1][dc*4+3]*inv1};
    *(f32x4*)&ZF[(size_t)(nbase + ty*2 + 0)*256 + dc*64 + tx*4] = w0;
    *(f32x4*)&ZF[(size_t)(nbase + ty*2 + 1)*256 + dc*64 + tx*4] = w1;
  }
}

// ---------------- gate + memory + pointer-mass (verified round-3) -----------
__global__ void n_gate(const float* __restrict__ ZF,
                       const float* __restrict__ Wc, const float* __restrict__ bc,
                       float* __restrict__ Mm, float* __restrict__ PSUM){
  __shared__ float r0[256], r1[256], r2[256];
  __shared__ float push_s;
  const int n = blockIdx.x, t = threadIdx.x;
  const float z = ZF[n*256 + t];
  r0[t] = z*Wc[t*3 + 0];
  r1[t] = z*Wc[t*3 + 1];
  r2[t] = z*Wc[t*3 + 2];
  __syncthreads();
  for (int s2 = 128; s2 > 0; s2 >>= 1){
    if (t < s2){ r0[t] += r0[t+s2]; r1[t] += r1[t+s2]; r2[t] += r2[t+s2]; }
    __syncthreads();
  }
  if (t == 0){
    float g0 = 1.f/(1.f + expf(-(r0[0] + bc[0])));
    float g1 = 1.f/(1.f + expf(-(r1[0] + bc[1])));
    float g2 = 1.f/(1.f + expf(-(r2[0] + bc[2])));
    float tt = g0 + g1 + g2, tot = tt + 1e-6f;
    push_s = g0/tot;
    PSUM[n] *= tt/tot;           // pointer mass with the NEW gates
  }
  __syncthreads();
  const float mo = Mm[n*256 + t];
  Mm[n*256 + t] = mo + push_s*(z - mo);   // (1-push)*m + push*zf
}

// ---------------------------------------------------------------------------
extern "C" void kernel_launch(void* const* d_in, const int* in_sizes, int n_in,
                              void* d_out, int out_size, void* d_ws, size_t ws_size,
                              hipStream_t stream){
  (void)in_sizes; (void)n_in; (void)out_size; (void)ws_size;
  const float* xr   = (const float*)d_in[0];
  const float* xi   = (const float*)d_in[1];
  const float* Wq_r = (const float*)d_in[2];
  const float* Wq_i = (const float*)d_in[3];
  const float* Wk_r = (const float*)d_in[4];
  const float* Wk_i = (const float*)d_in[5];
  const float* Wv_r = (const float*)d_in[6];
  const float* Wv_i = (const float*)d_in[7];
  // d_in[8..11] (Mq_*, Mk_*) unused: all stack slots identical -> memory
  // attention exactly uniform regardless of its q/k projections (verified r3).
  const float* Mv_r = (const float*)d_in[12];
  const float* Mv_i = (const float*)d_in[13];
  const float* Wc   = (const float*)d_in[14];
  const float* bc   = (const float*)d_in[15];
  const float* Wo   = (const float*)d_in[16];
  const float* bo   = (const float*)d_in[17];

  // Workspace layout identical in size to verified round 3 (41,975,808 B).
  uint8_t* w = (uint8_t*)d_ws;
  float* Z    = (float*)w; w += (size_t)8192*256*4;   // state; aliased as ZF
  float* QKV  = (float*)w; w += (size_t)8192*768*4;
  float* Mm   = (float*)w; w += (size_t)8192*256*4;
  float* PSUM = (float*)w; w += (size_t)8192*4;
  float* ZF   = Z;  // safe alias: state dead once proj consumed it; memread
                    // epilogue is per-element read-before-write by owner thread.

  k_init32<<<dim3(1024), dim3(256), 0, stream>>>(xr, xi, Z, Mm, PSUM);
  for (int t = 0; t < 8; ++t){
    k_gemm32<0><<<dim3(384), dim3(256), 0, stream>>>(Z, 6,
        Wq_r, Wq_i, Wk_r, Wk_i, Wv_r, Wv_i, QKV, nullptr, nullptr);
    k_attn32<<<dim3(256), dim3(256), 0, stream>>>(QKV, ZF);
    n_gate<<<dim3(8192), dim3(256), 0, stream>>>(ZF, Wc, bc, Mm, PSUM);
    k_gemm32<1><<<dim3(128), dim3(256), 0, stream>>>(Mm, 2,
        Mv_r, Mv_i, nullptr, nullptr, nullptr, nullptr, Z, PSUM, nullptr);
  }
  k_gemm32<2><<<dim3(64), dim3(256), 0, stream>>>(Z, 1,
      Wo, nullptr, nullptr, nullptr, nullptr, nullptr, (float*)d_out, nullptr, bo);
}